// Round 1
// baseline (2047.435 us; speedup 1.0000x reference)
//
#include <hip/hip_runtime.h>

typedef unsigned short u16;
typedef short v8s   __attribute__((ext_vector_type(8)));
typedef float f32x4 __attribute__((ext_vector_type(4)));
typedef float f32x2 __attribute__((ext_vector_type(2)));

#define H_ 256
#define B_ 8192
#define NSTEP 31
#define NTHREADS 512
#define NBLOCKS 256
#define AROW 264   // 256 + 8 bf16 pad -> 528B row stride, 16B aligned, 2-way max LDS conflicts

#define MFMA16(a,b,c) __builtin_amdgcn_mfma_f32_16x16x32_bf16(a,b,c,0,0,0)

__device__ __forceinline__ u16 f2bf(float f){
  unsigned u = __float_as_uint(f);
  u += 0x7fffu + ((u >> 16) & 1u);   // RNE
  return (u16)(u >> 16);
}

// ---- workspace layout (u16 units) ----
#define WS_W0   0        // [q][n][j]      4*256*8   = 8192   (W0 padded K->32, zeros k>=6)
#define WS_W1   8192     // [n][k]         256*256   = 65536  (Wh[0] column-major)
#define WS_W23  73728    // [l][kc][q][n][j] 2*8*4*256*8 = 131072 (Wh[1],Wh[2] frag-swizzled)
#define WS_WO   204800   // [kc][q][nn][j] 8*4*4*8   = 1024   (Wout padded N->4, col3=0)
#define WS_TOT  205824   // * 2 bytes = 411,648 B of d_ws

__global__ void prep_kernel(const float* __restrict__ W0,
                            const float* __restrict__ Wh,
                            const float* __restrict__ Wout,
                            u16* __restrict__ ws){
  int i = blockIdx.x * 256 + threadIdx.x;
  if (i < 8192){
    int q = i >> 11, n = (i >> 3) & 255, j = i & 7;
    int k = q*8 + j;
    ws[i] = f2bf(k < 6 ? W0[k*H_ + n] : 0.f);
  } else if (i < 73728){
    int r = i - 8192;
    int n = r >> 8, k = r & 255;
    ws[i] = f2bf(Wh[k*H_ + n]);                 // Wh[0] transposed -> [n][k]
  } else if (i < 204800){
    int r = i - 73728;
    int l = r >> 16, r2 = r & 65535;
    int kc = r2 >> 13, r3 = r2 & 8191;
    int q = r3 >> 11, n = (r3 >> 3) & 255, j = r3 & 7;
    int k = kc*32 + q*8 + j;
    ws[i] = f2bf(Wh[(1 + l)*H_*H_ + k*H_ + n]); // B-fragment order
  } else if (i < WS_TOT){
    int r = i - 204800;
    int kc = r >> 7, q = (r >> 5) & 3, nn = (r >> 3) & 3, j = r & 7;
    int k = kc*32 + q*8 + j;
    ws[i] = f2bf(nn < 3 ? Wout[k*3 + nn] : 0.f);
  }
}

// ---- LDS layout (bytes) ----
#define OFF_A      0        // 32*264*2  = 16896   activations, A-fragment order [m][k]
#define OFF_W1     16896    // 256*264*2 = 135168  Wh[0] as [n][k] + pad
#define OFF_WOUT   152064   // 2048
#define OFF_PART   154112   // [row 32][wave 8][2] f32 = 2048
#define OFF_MR     156160   // [row 32][mean,rstd]     = 256
#define OFF_NET    156416   // [32][4] f32
#define OFF_YCUR   156928
#define OFF_YSUM   157440
#define OFF_YSTG   157952
#define OFF_P      158464
#define OFF_DTS    158976   // 128
#define LDS_TOTAL  159104   // <= 163840

__global__ __launch_bounds__(NTHREADS, 2)
void pinode_kernel(const float* __restrict__ y0g, const float* __restrict__ t_span,
                   const float* __restrict__ params, const float* __restrict__ b0g,
                   const float* __restrict__ bhg, const float* __restrict__ ln_gg,
                   const float* __restrict__ ln_bg, const float* __restrict__ boutg,
                   const float* __restrict__ gatep, const u16* __restrict__ ws,
                   float* __restrict__ out)
{
  extern __shared__ char smem[];
  u16*   A    = (u16*)(smem + OFF_A);
  u16*   W1   = (u16*)(smem + OFF_W1);
  u16*   WO   = (u16*)(smem + OFF_WOUT);
  float* part = (float*)(smem + OFF_PART);
  float* mrs  = (float*)(smem + OFF_MR);
  float* net  = (float*)(smem + OFF_NET);
  float* ycur = (float*)(smem + OFF_YCUR);
  float* ysum = (float*)(smem + OFF_YSUM);
  float* ystg = (float*)(smem + OFF_YSTG);
  float* pL   = (float*)(smem + OFF_P);
  float* dts  = (float*)(smem + OFF_DTS);

  const int tid = threadIdx.x;
  const int wave = tid >> 6;
  const int lane = tid & 63;
  const int q    = lane >> 4;
  const int c15  = lane & 15;
  const int colbase = wave * 32;     // each wave owns 32 output columns
  const int s0 = blockIdx.x * 32;    // 32 samples per block, 256 blocks = 8192

  // ---- startup: stage W1 + Wout frags to LDS, load state ----
  for (int idx = tid; idx < 8192; idx += NTHREADS){
    int n = idx >> 5, ch = idx & 31;
    *(v8s*)(W1 + n*AROW + ch*8) = *(const v8s*)(ws + WS_W1 + n*256 + ch*8);
  }
  if (tid < 128)
    *(v8s*)(WO + tid*8) = *(const v8s*)(ws + WS_WO + tid*8);
  if (tid < 96){
    int s = tid & 31, c = tid >> 5;
    float y = y0g[(s0+s)*3 + c];
    ycur[s*4+c] = y; ystg[s*4+c] = y;
    pL[s*4+c]   = params[(s0+s)*3 + c];
    out[(s0+s)*3 + c] = y;                    // t=0 row
  }
  if (tid < NSTEP) dts[tid] = t_span[tid+1] - t_span[tid];

  // ---- weight fragments in registers: layers 2,3 (wf) + layer 0 (w0f) ----
  v8s wf[2][8][2];
#pragma unroll
  for (int l = 0; l < 2; ++l)
#pragma unroll
    for (int kc = 0; kc < 8; ++kc)
#pragma unroll
      for (int nt = 0; nt < 2; ++nt)
        wf[l][kc][nt] = *(const v8s*)(ws + WS_W23 +
            (((l*8 + kc)*4 + q)*256 + colbase + nt*16 + c15)*8);

  v8s w0f[2];
#pragma unroll
  for (int nt = 0; nt < 2; ++nt)
    w0f[nt] = *(const v8s*)(ws + WS_W0 + (q*256 + colbase + nt*16 + c15)*8);

  float lng[4][2], lnb[4][2], bia[4][2];
#pragma unroll
  for (int l = 0; l < 4; ++l)
#pragma unroll
    for (int nt = 0; nt < 2; ++nt){
      int col = colbase + nt*16 + c15;
      lng[l][nt] = ln_gg[l*H_ + col];
      lnb[l][nt] = ln_bg[l*H_ + col];
      bia[l][nt] = (l == 0) ? b0g[col] : bhg[(l-1)*H_ + col];
    }
  const float gate = gatep[0];
  const float bo0 = boutg[0], bo1 = boutg[1], bo2 = boutg[2];
  const f32x4 fzero = {0.f, 0.f, 0.f, 0.f};

  __syncthreads();

  // fill A-buffer rows 0..31 entries: [y(3), p(3), zeros...] in bf16
  auto fillA = [&](){
    int s = tid >> 4, pr = tid & 15;
    int e0 = pr*2, e1 = e0 + 1;
    float x0 = (e0 < 3) ? ystg[s*4+e0] : ((e0 < 6) ? pL[s*4+e0-3] : 0.f);
    float x1 = (e1 < 3) ? ystg[s*4+e1] : ((e1 < 6) ? pL[s*4+e1-3] : 0.f);
    unsigned pk = (unsigned)f2bf(x0) | ((unsigned)f2bf(x1) << 16);
    *(unsigned*)(A + s*AROW + e0) = pk;
  };

  fillA();
  __syncthreads();

  // LayerNorm + SiLU + bf16 store to A. acc holds h (bias already added).
  auto ln_silu = [&](f32x4 (&acc)[2][2], float g0, float g1, float bb0, float bb1){
    float rs[2][4], rq[2][4];
#pragma unroll
    for (int mt = 0; mt < 2; ++mt)
#pragma unroll
      for (int r = 0; r < 4; ++r){
        float a0 = acc[mt][0][r], a1 = acc[mt][1][r];
        rs[mt][r] = a0 + a1;
        rq[mt][r] = a0*a0 + a1*a1;
      }
#pragma unroll
    for (int m = 1; m < 16; m <<= 1)
#pragma unroll
      for (int mt = 0; mt < 2; ++mt)
#pragma unroll
        for (int r = 0; r < 4; ++r){
          rs[mt][r] += __shfl_xor(rs[mt][r], m, 16);
          rq[mt][r] += __shfl_xor(rq[mt][r], m, 16);
        }
    if (c15 == 0){
#pragma unroll
      for (int mt = 0; mt < 2; ++mt)
#pragma unroll
        for (int r = 0; r < 4; ++r){
          int row = mt*16 + q*4 + r;
          f32x2 v; v.x = rs[mt][r]; v.y = rq[mt][r];
          *(f32x2*)(part + (row*8 + wave)*2) = v;
        }
    }
    __syncthreads();
    if (tid < 32){
      const f32x4* pp = (const f32x4*)(part + tid*16);
      f32x4 p0 = pp[0], p1 = pp[1], p2 = pp[2], p3 = pp[3];
      float S = p0[0]+p0[2]+p1[0]+p1[2]+p2[0]+p2[2]+p3[0]+p3[2];
      float Q = p0[1]+p0[3]+p1[1]+p1[3]+p2[1]+p2[3]+p3[1]+p3[3];
      float mean = S * (1.f/256.f);
      float var  = Q * (1.f/256.f) - mean*mean;
      float rstd = rsqrtf(var + 1e-5f);
      f32x2 mr; mr.x = mean; mr.y = rstd;
      *(f32x2*)(mrs + tid*2) = mr;
    }
    __syncthreads();
#pragma unroll
    for (int mt = 0; mt < 2; ++mt)
#pragma unroll
      for (int r = 0; r < 4; ++r){
        int row = mt*16 + q*4 + r;
        f32x2 mr = *(const f32x2*)(mrs + row*2);
#pragma unroll
        for (int nt = 0; nt < 2; ++nt){
          float g  = nt ? g1 : g0;
          float bb = nt ? bb1 : bb0;
          float v  = (acc[mt][nt][r] - mr.x) * mr.y * g + bb;
          float sv = __fdividef(v, 1.f + __expf(-v));   // silu
          A[row*AROW + colbase + nt*16 + c15] = f2bf(sv);
        }
      }
    __syncthreads();
  };

#pragma unroll 1
  for (int step = 0; step < NSTEP; ++step){
    float dt = dts[step];
#pragma unroll 1
    for (int stage = 0; stage < 4; ++stage){
      f32x4 acc[2][2];

      // ---- layer 0: X(6, zero-padded to 32) @ W0 ----
#pragma unroll
      for (int mt = 0; mt < 2; ++mt)
#pragma unroll
        for (int nt = 0; nt < 2; ++nt) acc[mt][nt] = fzero;
      {
        v8s a0 = *(const v8s*)(A + c15*AROW + q*8);
        v8s a1 = *(const v8s*)(A + (16 + c15)*AROW + q*8);
        acc[0][0] = MFMA16(a0, w0f[0], acc[0][0]);
        acc[0][1] = MFMA16(a0, w0f[1], acc[0][1]);
        acc[1][0] = MFMA16(a1, w0f[0], acc[1][0]);
        acc[1][1] = MFMA16(a1, w0f[1], acc[1][1]);
      }
#pragma unroll
      for (int mt = 0; mt < 2; ++mt)
#pragma unroll
        for (int nt = 0; nt < 2; ++nt)
#pragma unroll
          for (int r = 0; r < 4; ++r) acc[mt][nt][r] += bia[0][nt];
      ln_silu(acc, lng[0][0], lng[0][1], lnb[0][0], lnb[0][1]);

      // ---- layer 1: weights from LDS ----
#pragma unroll
      for (int mt = 0; mt < 2; ++mt)
#pragma unroll
        for (int nt = 0; nt < 2; ++nt) acc[mt][nt] = fzero;
#pragma unroll
      for (int kc = 0; kc < 8; ++kc){
        v8s a0 = *(const v8s*)(A + c15*AROW + kc*32 + q*8);
        v8s a1 = *(const v8s*)(A + (16 + c15)*AROW + kc*32 + q*8);
        v8s bb0 = *(const v8s*)(W1 + (colbase + c15)*AROW + kc*32 + q*8);
        v8s bb1 = *(const v8s*)(W1 + (colbase + 16 + c15)*AROW + kc*32 + q*8);
        acc[0][0] = MFMA16(a0, bb0, acc[0][0]);
        acc[0][1] = MFMA16(a0, bb1, acc[0][1]);
        acc[1][0] = MFMA16(a1, bb0, acc[1][0]);
        acc[1][1] = MFMA16(a1, bb1, acc[1][1]);
      }
#pragma unroll
      for (int mt = 0; mt < 2; ++mt)
#pragma unroll
        for (int nt = 0; nt < 2; ++nt)
#pragma unroll
          for (int r = 0; r < 4; ++r) acc[mt][nt][r] += bia[1][nt];
      ln_silu(acc, lng[1][0], lng[1][1], lnb[1][0], lnb[1][1]);

      // ---- layers 2,3: weights from registers ----
#pragma unroll
      for (int l = 0; l < 2; ++l){
#pragma unroll
        for (int mt = 0; mt < 2; ++mt)
#pragma unroll
          for (int nt = 0; nt < 2; ++nt) acc[mt][nt] = fzero;
#pragma unroll
        for (int kc = 0; kc < 8; ++kc){
          v8s a0 = *(const v8s*)(A + c15*AROW + kc*32 + q*8);
          v8s a1 = *(const v8s*)(A + (16 + c15)*AROW + kc*32 + q*8);
          acc[0][0] = MFMA16(a0, wf[l][kc][0], acc[0][0]);
          acc[0][1] = MFMA16(a0, wf[l][kc][1], acc[0][1]);
          acc[1][0] = MFMA16(a1, wf[l][kc][0], acc[1][0]);
          acc[1][1] = MFMA16(a1, wf[l][kc][1], acc[1][1]);
        }
#pragma unroll
        for (int mt = 0; mt < 2; ++mt)
#pragma unroll
          for (int nt = 0; nt < 2; ++nt)
#pragma unroll
            for (int r = 0; r < 4; ++r) acc[mt][nt][r] += bia[2+l][nt];
        ln_silu(acc, lng[2+l][0], lng[2+l][1], lnb[2+l][0], lnb[2+l][1]);
      }

      // ---- output layer: h @ Wout (waves 0,1 only; cols>=3 are zero weights) ----
      if (wave < 2){
        f32x4 ao = fzero;
        int nn = c15 < 3 ? c15 : 3;
#pragma unroll
        for (int kc = 0; kc < 8; ++kc){
          v8s a = *(const v8s*)(A + (wave*16 + c15)*AROW + kc*32 + q*8);
          v8s b = *(const v8s*)(WO + ((kc*4 + q)*4 + nn)*8);
          ao = MFMA16(a, b, ao);
        }
        if (c15 < 3){
#pragma unroll
          for (int r = 0; r < 4; ++r)
            net[(wave*16 + q*4 + r)*4 + c15] = ao[r];
        }
      }
      __syncthreads();

      // ---- RK4 bookkeeping: one thread per sample (no cross-thread hazards) ----
      if (tid < 32){
        int s = tid;
        float u = ystg[s*4+0], v = ystg[s*4+1], w = ystg[s*4+2];
        float Om = pL[s*4+0], ga = pL[s*4+2];
        float kk[3];
        kk[0] = -ga*u                      + gate*(net[s*4+0] + bo0);
        kk[1] = -ga*v - Om*w               + gate*(net[s*4+1] + bo1);
        kk[2] = -2.f*ga*(w + 1.f) + Om*v   + gate*(net[s*4+2] + bo2);
#pragma unroll
        for (int c = 0; c < 3; ++c){
          float yc = ycur[s*4+c];
          float k  = kk[c];
          float accw = (stage == 0) ? (yc + dt*(1.f/6.f)*k)
                     : (ysum[s*4+c] + ((stage == 3) ? dt*(1.f/6.f) : dt*(1.f/3.f))*k);
          if (stage == 3){
            ycur[s*4+c] = accw;
            ystg[s*4+c] = accw;
            out[(step+1)*(B_*3) + (s0+s)*3 + c] = accw;
          } else {
            ysum[s*4+c] = accw;
            ystg[s*4+c] = yc + ((stage == 2) ? dt : 0.5f*dt)*k;
          }
        }
      }
      __syncthreads();
      fillA();
      __syncthreads();
    }
  }
}

extern "C" void kernel_launch(void* const* d_in, const int* in_sizes, int n_in,
                              void* d_out, int out_size, void* d_ws, size_t ws_size,
                              hipStream_t stream) {
  const float* y0     = (const float*)d_in[0];
  const float* t_span = (const float*)d_in[1];
  const float* params = (const float*)d_in[2];
  const float* W0     = (const float*)d_in[3];
  const float* b0     = (const float*)d_in[4];
  const float* Wh     = (const float*)d_in[5];
  const float* bh     = (const float*)d_in[6];
  const float* ln_g   = (const float*)d_in[7];
  const float* ln_b   = (const float*)d_in[8];
  const float* Wout   = (const float*)d_in[9];
  const float* bout   = (const float*)d_in[10];
  const float* gate   = (const float*)d_in[11];
  float* out = (float*)d_out;
  u16* ws = (u16*)d_ws;

  prep_kernel<<<WS_TOT/256, 256, 0, stream>>>(W0, Wh, Wout, ws);

  hipFuncSetAttribute(reinterpret_cast<const void*>(pinode_kernel),
                      hipFuncAttributeMaxDynamicSharedMemorySize, LDS_TOTAL);
  pinode_kernel<<<NBLOCKS, NTHREADS, LDS_TOTAL, stream>>>(
      y0, t_span, params, b0, bh, ln_g, ln_b, bout, gate, ws, out);
}

// Round 2
// 1167.609 us; speedup vs baseline: 1.7535x; 1.7535x over previous
//
#include <hip/hip_runtime.h>

typedef unsigned short u16;
typedef short v8s   __attribute__((ext_vector_type(8)));
typedef float f32x4 __attribute__((ext_vector_type(4)));
typedef float f32x2 __attribute__((ext_vector_type(2)));

#define H_ 256
#define B_ 8192
#define NSTEP 31
#define NTHREADS 512
#define NBLOCKS 256
#define AROW 264   // 256 + 8 bf16 pad -> 528B row stride (33x16B, odd) -> conflict-free b128 reads

#define MFMA16(a,b,c) __builtin_amdgcn_mfma_f32_16x16x32_bf16(a,b,c,0,0,0)

// DPP controls
#define DPP_QP_XOR1 0xB1   // quad_perm(1,0,3,2)
#define DPP_QP_XOR2 0x4E   // quad_perm(2,3,0,1)
#define DPP_ROR4    0x124  // row_ror:4
#define DPP_ROR8    0x128  // row_ror:8

template<int CTRL>
__device__ __forceinline__ float dpp_add(float v){
  return v + __int_as_float(
      __builtin_amdgcn_update_dpp(0, __float_as_int(v), CTRL, 0xF, 0xF, true));
}

__device__ __forceinline__ u16 f2bf_rne(float f){
  unsigned u = __float_as_uint(f);
  u += 0x7fffu + ((u >> 16) & 1u);
  return (u16)(u >> 16);
}
__device__ __forceinline__ u16 f2bf_trunc(float f){
  return (u16)(__float_as_uint(f) >> 16);
}

// ---- workspace layout (u16 units) ----
#define WS_W0   0        // [q][n][j] 4*256*8 = 8192 (W0 padded K->32; k==6 row = b0)
#define WS_W1   8192     // [n][k]   256*256 = 65536 (Wh[0] transposed)
#define WS_W23  73728    // [l][kc][q][n][j] 2*8*4*256*8 = 131072
#define WS_WO   204800   // [kc][q][nn][j] 8*4*4*8 = 1024
#define WS_TOT  205824

__global__ void prep_kernel(const float* __restrict__ W0,
                            const float* __restrict__ b0,
                            const float* __restrict__ Wh,
                            const float* __restrict__ Wout,
                            u16* __restrict__ ws){
  int i = blockIdx.x * 256 + threadIdx.x;
  if (i < 8192){
    int q = i >> 11, n = (i >> 3) & 255, j = i & 7;
    int k = q*8 + j;
    float v = (k < 6) ? W0[k*H_ + n] : ((k == 6) ? b0[n] : 0.f);
    ws[i] = f2bf_rne(v);
  } else if (i < 73728){
    int r = i - 8192;
    int n = r >> 8, k = r & 255;
    ws[i] = f2bf_rne(Wh[k*H_ + n]);
  } else if (i < 204800){
    int r = i - 73728;
    int l = r >> 16, r2 = r & 65535;
    int kc = r2 >> 13, r3 = r2 & 8191;
    int q = r3 >> 11, n = (r3 >> 3) & 255, j = r3 & 7;
    int k = kc*32 + q*8 + j;
    ws[i] = f2bf_rne(Wh[(1 + l)*H_*H_ + k*H_ + n]);
  } else if (i < WS_TOT){
    int r = i - 204800;
    int kc = r >> 7, q = (r >> 5) & 3, nn = (r >> 3) & 3, j = r & 7;
    int k = kc*32 + q*8 + j;
    ws[i] = f2bf_rne(nn < 3 ? Wout[k*3 + nn] : 0.f);
  }
}

// ---- LDS layout (bytes) ----
#define PWROW 10            // partials stride per row in f32x2 units (pad 8->10, kills 16-way conflict)
#define OFF_A      0        // 16896
#define OFF_W1     16896    // 135168
#define OFF_WOUT   152064   // 2048
#define OFF_PART   154112   // 32*PWROW*8 = 2560
#define OFF_MR     156672   // 256
#define OFF_NET    156928   // 512
#define OFF_YCUR   157440   // 512
#define OFF_YSUM   157952   // 512
#define OFF_YSTG   158464   // 512
#define OFF_P      158976   // 512
#define OFF_DTS    159488   // 128
#define LDS_TOTAL  159616

__global__ __launch_bounds__(NTHREADS, 2)
void pinode_kernel(const float* __restrict__ y0g, const float* __restrict__ t_span,
                   const float* __restrict__ params, const float* __restrict__ bhg,
                   const float* __restrict__ ln_gg, const float* __restrict__ ln_bg,
                   const float* __restrict__ boutg, const float* __restrict__ gatep,
                   const u16* __restrict__ ws, float* __restrict__ out)
{
  extern __shared__ char smem[];
  u16*   A    = (u16*)(smem + OFF_A);
  u16*   W1   = (u16*)(smem + OFF_W1);
  u16*   WO   = (u16*)(smem + OFF_WOUT);
  float* part = (float*)(smem + OFF_PART);
  float* mrs  = (float*)(smem + OFF_MR);
  float* net  = (float*)(smem + OFF_NET);
  float* ycur = (float*)(smem + OFF_YCUR);
  float* ysum = (float*)(smem + OFF_YSUM);
  float* ystg = (float*)(smem + OFF_YSTG);
  float* pL   = (float*)(smem + OFF_P);
  float* dts  = (float*)(smem + OFF_DTS);

  const int tid = threadIdx.x;
  const int wave = tid >> 6;
  const int lane = tid & 63;
  const int q    = lane >> 4;
  const int c15  = lane & 15;
  const int colbase = wave * 32;
  const int s0 = blockIdx.x * 32;

  for (int idx = tid; idx < 8192; idx += NTHREADS){
    int n = idx >> 5, ch = idx & 31;
    *(v8s*)(W1 + n*AROW + ch*8) = *(const v8s*)(ws + WS_W1 + n*256 + ch*8);
  }
  if (tid < 128)
    *(v8s*)(WO + tid*8) = *(const v8s*)(ws + WS_WO + tid*8);
  if (tid < 96){
    int s = tid & 31, c = tid >> 5;
    float y = y0g[(s0+s)*3 + c];
    ycur[s*4+c] = y; ystg[s*4+c] = y;
    pL[s*4+c]   = params[(s0+s)*3 + c];
    out[(s0+s)*3 + c] = y;
  }
  if (tid < NSTEP) dts[tid] = t_span[tid+1] - t_span[tid];

  v8s wf[2][8][2];
#pragma unroll
  for (int l = 0; l < 2; ++l)
#pragma unroll
    for (int kc = 0; kc < 8; ++kc)
#pragma unroll
      for (int nt = 0; nt < 2; ++nt)
        wf[l][kc][nt] = *(const v8s*)(ws + WS_W23 +
            (((l*8 + kc)*4 + q)*256 + colbase + nt*16 + c15)*8);

  v8s w0f[2];
#pragma unroll
  for (int nt = 0; nt < 2; ++nt)
    w0f[nt] = *(const v8s*)(ws + WS_W0 + (q*256 + colbase + nt*16 + c15)*8);

  float lng[4][2], lnb[4][2], bia[4][2];
#pragma unroll
  for (int l = 0; l < 4; ++l)
#pragma unroll
    for (int nt = 0; nt < 2; ++nt){
      int col = colbase + nt*16 + c15;
      lng[l][nt] = ln_gg[l*H_ + col];
      lnb[l][nt] = ln_bg[l*H_ + col];
      bia[l][nt] = (l == 0) ? 0.f : bhg[(l-1)*H_ + col];  // b0 folded into W0 row 6
    }
  const float gate = gatep[0];
  const float bo0 = boutg[0], bo1 = boutg[1], bo2 = boutg[2];
  const f32x4 fzero = {0.f, 0.f, 0.f, 0.f};

  // loop-invariant LDS base pointers
  const u16* pa  = A + c15*AROW + q*8;                     // A-frag rows 0..15
  const u16* pw  = W1 + (colbase + c15)*AROW + q*8;        // W1 frag base
  u16* pstA = A + (q*4)*AROW + colbase + c15;              // LN store base

  __syncthreads();

  // initial A fill: [y(3), p(3), 1.0 (bias lane), zeros]
  {
    int s = tid >> 4, pr = tid & 15;
    int e0 = pr*2, e1 = e0 + 1;
    float x0 = (e0 < 3) ? ystg[s*4+e0] : ((e0 < 6) ? pL[s*4+e0-3] : (e0 == 6 ? 1.f : 0.f));
    float x1 = (e1 < 3) ? ystg[s*4+e1] : ((e1 < 6) ? pL[s*4+e1-3] : (e1 == 6 ? 1.f : 0.f));
    unsigned pk = (unsigned)f2bf_rne(x0) | ((unsigned)f2bf_rne(x1) << 16);
    *(unsigned*)(A + s*AROW + e0) = pk;
  }
  __syncthreads();

  // LayerNorm + SiLU + bf16 store to A
  auto ln_silu = [&](f32x4 (&acc)[2][2], int li){
    float rs[2][4], rq[2][4];
#pragma unroll
    for (int mt = 0; mt < 2; ++mt)
#pragma unroll
      for (int r = 0; r < 4; ++r){
        float a0 = acc[mt][0][r], a1 = acc[mt][1][r];
        rs[mt][r] = a0 + a1;
        rq[mt][r] = a0*a0 + a1*a1;
      }
    // DPP allreduce over the 16-lane c15 group (pure VALU)
#pragma unroll
    for (int mt = 0; mt < 2; ++mt)
#pragma unroll
      for (int r = 0; r < 4; ++r){
        float s = rs[mt][r], qq = rq[mt][r];
        s = dpp_add<DPP_QP_XOR1>(s);  qq = dpp_add<DPP_QP_XOR1>(qq);
        s = dpp_add<DPP_QP_XOR2>(s);  qq = dpp_add<DPP_QP_XOR2>(qq);
        s = dpp_add<DPP_ROR4>(s);     qq = dpp_add<DPP_ROR4>(qq);
        s = dpp_add<DPP_ROR8>(s);     qq = dpp_add<DPP_ROR8>(qq);
        rs[mt][r] = s; rq[mt][r] = qq;
      }
    if (c15 == 0){
#pragma unroll
      for (int mt = 0; mt < 2; ++mt)
#pragma unroll
        for (int r = 0; r < 4; ++r){
          int row = mt*16 + q*4 + r;
          f32x2 v; v.x = rs[mt][r]; v.y = rq[mt][r];
          *(f32x2*)(part + (row*PWROW + wave)*2) = v;
        }
    }
    __syncthreads();
    if (tid < 32){
      const f32x4* pp = (const f32x4*)(part + tid*PWROW*2);
      f32x4 p0 = pp[0], p1 = pp[1], p2 = pp[2], p3 = pp[3];
      float S = p0[0]+p0[2]+p1[0]+p1[2]+p2[0]+p2[2]+p3[0]+p3[2];
      float Q = p0[1]+p0[3]+p1[1]+p1[3]+p2[1]+p2[3]+p3[1]+p3[3];
      float mean = S * (1.f/256.f);
      float var  = Q * (1.f/256.f) - mean*mean;
      float rstd = rsqrtf(var + 1e-5f);
      f32x2 mr; mr.x = rstd; mr.y = -mean*rstd;   // store (rstd, -mu*rstd)
      *(f32x2*)(mrs + tid*2) = mr;
    }
    __syncthreads();
#pragma unroll
    for (int mt = 0; mt < 2; ++mt)
#pragma unroll
      for (int r = 0; r < 4; ++r){
        int row = mt*16 + q*4 + r;
        f32x2 mr = *(const f32x2*)(mrs + row*2);
#pragma unroll
        for (int nt = 0; nt < 2; ++nt){
          float t  = acc[mt][nt][r] * mr.x + mr.y;           // (a-mu)*rstd
          float v  = t * lng[li][nt] + lnb[li][nt];          // *g+b
          float e  = __builtin_amdgcn_exp2f(v * -1.44269504f);
          float sv = v * __builtin_amdgcn_rcpf(1.f + e);     // silu
          pstA[(mt*16 + r)*AROW + nt*16] = f2bf_trunc(sv);
        }
      }
    __syncthreads();
  };

#pragma unroll 1
  for (int step = 0; step < NSTEP; ++step){
    float dt = dts[step];
#pragma unroll 1
    for (int stage = 0; stage < 4; ++stage){
      f32x4 acc[2][2];

      // ---- layer 0: X(7 used, zero-padded to 32) @ W0' (bias row included) ----
#pragma unroll
      for (int mt = 0; mt < 2; ++mt)
#pragma unroll
        for (int nt = 0; nt < 2; ++nt) acc[mt][nt] = fzero;
      {
        v8s a0 = *(const v8s*)(pa);
        v8s a1 = *(const v8s*)(pa + 16*AROW);
        acc[0][0] = MFMA16(a0, w0f[0], acc[0][0]);
        acc[0][1] = MFMA16(a0, w0f[1], acc[0][1]);
        acc[1][0] = MFMA16(a1, w0f[0], acc[1][0]);
        acc[1][1] = MFMA16(a1, w0f[1], acc[1][1]);
      }
      ln_silu(acc, 0);

      // ---- layer 1: weights from LDS ----
#pragma unroll
      for (int mt = 0; mt < 2; ++mt)
#pragma unroll
        for (int nt = 0; nt < 2; ++nt) acc[mt][nt] = fzero;
#pragma unroll
      for (int kc = 0; kc < 8; ++kc){
        v8s a0 = *(const v8s*)(pa + kc*32);
        v8s a1 = *(const v8s*)(pa + 16*AROW + kc*32);
        v8s bb0 = *(const v8s*)(pw + kc*32);
        v8s bb1 = *(const v8s*)(pw + 16*AROW + kc*32);
        acc[0][0] = MFMA16(a0, bb0, acc[0][0]);
        acc[0][1] = MFMA16(a0, bb1, acc[0][1]);
        acc[1][0] = MFMA16(a1, bb0, acc[1][0]);
        acc[1][1] = MFMA16(a1, bb1, acc[1][1]);
      }
#pragma unroll
      for (int mt = 0; mt < 2; ++mt)
#pragma unroll
        for (int nt = 0; nt < 2; ++nt)
#pragma unroll
          for (int r = 0; r < 4; ++r) acc[mt][nt][r] += bia[1][nt];
      ln_silu(acc, 1);

      // ---- layers 2,3: weights from registers ----
#pragma unroll
      for (int l = 0; l < 2; ++l){
#pragma unroll
        for (int mt = 0; mt < 2; ++mt)
#pragma unroll
          for (int nt = 0; nt < 2; ++nt) acc[mt][nt] = fzero;
#pragma unroll
        for (int kc = 0; kc < 8; ++kc){
          v8s a0 = *(const v8s*)(pa + kc*32);
          v8s a1 = *(const v8s*)(pa + 16*AROW + kc*32);
          acc[0][0] = MFMA16(a0, wf[l][kc][0], acc[0][0]);
          acc[0][1] = MFMA16(a0, wf[l][kc][1], acc[0][1]);
          acc[1][0] = MFMA16(a1, wf[l][kc][0], acc[1][0]);
          acc[1][1] = MFMA16(a1, wf[l][kc][1], acc[1][1]);
        }
#pragma unroll
        for (int mt = 0; mt < 2; ++mt)
#pragma unroll
          for (int nt = 0; nt < 2; ++nt)
#pragma unroll
            for (int r = 0; r < 4; ++r) acc[mt][nt][r] += bia[2+l][nt];
        ln_silu(acc, 2+l);
      }

      // ---- output layer: h @ Wout (waves 0,1) ----
      if (wave < 2){
        f32x4 ao = fzero;
        int nn = c15 < 3 ? c15 : 3;
#pragma unroll
        for (int kc = 0; kc < 8; ++kc){
          v8s a = *(const v8s*)(A + (wave*16 + c15)*AROW + kc*32 + q*8);
          v8s b = *(const v8s*)(WO + ((kc*4 + q)*4 + nn)*8);
          ao = MFMA16(a, b, ao);
        }
        if (c15 < 3){
#pragma unroll
          for (int r = 0; r < 4; ++r)
            net[(wave*16 + q*4 + r)*4 + c15] = ao[r];
        }
      }
      __syncthreads();

      // ---- RK4 bookkeeping + direct y write into A (replaces fillA) ----
      if (tid < 32){
        int s = tid;
        float u = ystg[s*4+0], v = ystg[s*4+1], w = ystg[s*4+2];
        float Om = pL[s*4+0], ga = pL[s*4+2];
        float kk[3];
        kk[0] = -ga*u                      + gate*(net[s*4+0] + bo0);
        kk[1] = -ga*v - Om*w               + gate*(net[s*4+1] + bo1);
        kk[2] = -2.f*ga*(w + 1.f) + Om*v   + gate*(net[s*4+2] + bo2);
#pragma unroll
        for (int c = 0; c < 3; ++c){
          float yc = ycur[s*4+c];
          float k  = kk[c];
          float ys;
          if (stage == 3){
            float accw = ysum[s*4+c] + dt*(1.f/6.f)*k;
            ycur[s*4+c] = accw;
            ys = accw;
            out[(step+1)*(B_*3) + (s0+s)*3 + c] = accw;
          } else {
            float accw = (stage == 0) ? (yc + dt*(1.f/6.f)*k)
                                      : (ysum[s*4+c] + dt*(1.f/3.f)*k);
            ysum[s*4+c] = accw;
            ys = yc + ((stage == 2) ? dt : 0.5f*dt)*k;
          }
          ystg[s*4+c] = ys;
          A[s*AROW + c] = f2bf_rne(ys);
        }
      }
      __syncthreads();
    }
  }
}

extern "C" void kernel_launch(void* const* d_in, const int* in_sizes, int n_in,
                              void* d_out, int out_size, void* d_ws, size_t ws_size,
                              hipStream_t stream) {
  const float* y0     = (const float*)d_in[0];
  const float* t_span = (const float*)d_in[1];
  const float* params = (const float*)d_in[2];
  const float* W0     = (const float*)d_in[3];
  const float* b0     = (const float*)d_in[4];
  const float* Wh     = (const float*)d_in[5];
  const float* bh     = (const float*)d_in[6];
  const float* ln_g   = (const float*)d_in[7];
  const float* ln_b   = (const float*)d_in[8];
  const float* Wout   = (const float*)d_in[9];
  const float* bout   = (const float*)d_in[10];
  const float* gate   = (const float*)d_in[11];
  float* out = (float*)d_out;
  u16* ws = (u16*)d_ws;

  prep_kernel<<<WS_TOT/256, 256, 0, stream>>>(W0, b0, Wh, Wout, ws);

  hipFuncSetAttribute(reinterpret_cast<const void*>(pinode_kernel),
                      hipFuncAttributeMaxDynamicSharedMemorySize, LDS_TOTAL);
  pinode_kernel<<<NBLOCKS, NTHREADS, LDS_TOTAL, stream>>>(
      y0, t_span, params, bh, ln_g, ln_b, bout, gate, ws, out);
}